// Round 10
// baseline (5445.049 us; speedup 1.0000x reference)
//
#include <hip/hip_runtime.h>
#include <hip/hip_bf16.h>
#include <stdint.h>

typedef __bf16 bf16x8 __attribute__((ext_vector_type(8)));
typedef float  f32x4  __attribute__((ext_vector_type(4)));

#define MFMA16(a, b, c) __builtin_amdgcn_mfma_f32_16x16x32_bf16((a), (b), (c), 0, 0, 0)

namespace {
constexpr int T_   = 80;
constexpr int B_   = 4096;
constexpr int H_   = 256;
constexpr int HP_  = 264;   // padded LDS row stride
constexpr int V_   = 80;
constexpr int RF   = 16;    // fallback kernel: rows/block
constexpr int RC   = 32;    // coop kernel: rows per partner-pair tile
constexpr int NH   = 128;   // half of H (N-split width)
constexpr int NTILE = 128;  // batch tiles (B_/RC)
constexpr int OUT_HN = B_ * V_;
constexpr int OUT_CN = OUT_HN + 2 * B_ * H_;

// ---- WAVE-CONTIGUOUS weight layout (R6, proven) ----
// Fragment = 32 B = [hi bf16 x8][lo bf16 x8] for one (gate-row, 8 K-elems).
// K=256 tensors: fragment (coltile t=0..15, k=0..7, g=0..3, quad, m) covers
// W[g*256 + t*16 + m][k*32 + quad*8 .. +8] at byte
// base + ((t*8+k)*4+g)*2048 + (quad*16+m)*32  -> one 2 KB wave-block.
// Wih0 (K=8): (t, g, m) -> byte base + (t*4+g)*512 + m*32.
constexpr size_t WB_WHH0 = 0;                    // 1 MB
constexpr size_t WB_WIH1 = (size_t)1 << 20;      // 1 MB
constexpr size_t WB_WHH1 = (size_t)2 << 20;      // 1 MB
constexpr size_t WB_WIH0 = (size_t)3 << 20;      // 32 KB
constexpr int WS_PLANE = 794624;                 // total weight elems (grid size)
constexpr size_t WSB_XCHG  = 3178496;
constexpr size_t XCHG_U32  = (size_t)RC * NH;    // 4096 u32 per slot
constexpr size_t WSB_FLAGS = WSB_XCHG + (size_t)2 * 2 * NTILE * 2 * XCHG_U32 * 4;
constexpr int    CTRL_U32  = 512 + 256 + 8;
constexpr size_t WSB_TOTAL = WSB_FLAGS + (size_t)CTRL_U32 * 4;
}

__device__ __forceinline__ float sigm_(float x) { return 1.0f / (1.0f + __expf(-x)); }
__device__ __forceinline__ float tanh_(float x) {
  x = fminf(fmaxf(x, -15.f), 15.f);
  float e = __expf(2.f * x);
  return (e - 1.f) / (e + 1.f);
}

__device__ __forceinline__ void split_(float w, __hip_bfloat16* hi, __hip_bfloat16* lo) {
  __hip_bfloat16 h = __float2bfloat16(w);
  *hi = h;
  *lo = __float2bfloat16(w - __bfloat162float(h));
}

__device__ __forceinline__ uint32_t pack2_(__hip_bfloat16 hi, __hip_bfloat16 lo) {
  return (uint32_t)__builtin_bit_cast(unsigned short, hi) |
         ((uint32_t)__builtin_bit_cast(unsigned short, lo) << 16);
}
__device__ __forceinline__ __hip_bfloat16 ubf_(unsigned short v) {
  return __builtin_bit_cast(__hip_bfloat16, v);
}

// load one 32 B fragment (hi 16 B + lo 16 B, same cache line)
__device__ __forceinline__ void ldfrag_(const char* pp, bf16x8* h, bf16x8* l) {
  *h = *(const bf16x8*)pp;
  *l = *(const bf16x8*)(pp + 16);
}

// K=256 tensor: elem e (row-major [1024][256]) -> byte offset in packed layout
__device__ __forceinline__ size_t addrK256_(int e) {
  int row = e >> 8, kk = e & 255;
  int g = row >> 8, cb = row & 255, t = cb >> 4, m = cb & 15;
  int k = kk >> 5, quad = (kk >> 3) & 3, j = kk & 7;
  return (size_t)(((t * 8 + k) * 4 + g)) * 2048 + (size_t)((quad * 16 + m) * 32 + j * 2);
}

// weight pre-split + repack pass; optionally zero sync/ctrl
__global__ __launch_bounds__(256) void cvt_pair(
    const float* __restrict__ Wih0f, const float* __restrict__ Whh0f,
    const float* __restrict__ Wih1f, const float* __restrict__ Whh1f,
    __hip_bfloat16* __restrict__ ws, int zero_flags)
{
  if (zero_flags && blockIdx.x < 4) {
    uint32_t* fl = (uint32_t*)((char*)ws + WSB_FLAGS);
    int idx = blockIdx.x * 256 + threadIdx.x;
    if (idx < CTRL_U32) fl[idx] = 0u;
  }
  int i = blockIdx.x * 256 + threadIdx.x;
  if (i >= WS_PLANE) return;
  char* wb = (char*)ws;
  float v; size_t off;
  if (i < 262144) {
    v = Whh0f[i];            off = WB_WHH0 + addrK256_(i);
  } else if (i < 524288) {
    int e = i - 262144;
    v = Wih1f[e];            off = WB_WIH1 + addrK256_(e);
  } else if (i < 786432) {
    int e = i - 524288;
    v = Whh1f[e];            off = WB_WHH1 + addrK256_(e);
  } else {
    int e = i - 786432;      // Wih0: [1024][8]
    int row = e >> 3, j = e & 7;
    int g = row >> 8, cb = row & 255, t = cb >> 4, m = cb & 15;
    v = Wih0f[e];
    off = WB_WIH0 + (size_t)((t * 4 + g) * 512 + m * 32 + j * 2);
  }
  __hip_bfloat16 hi = __float2bfloat16(v);
  *(__hip_bfloat16*)(wb + off)      = hi;
  *(__hip_bfloat16*)(wb + off + 16) = __float2bfloat16(v - __bfloat162float(hi));
}

// acc += (Ahi+Alo)*(Bhi+Blo), dropping lo*lo (3 MFMAs)
__device__ __forceinline__ f32x4 tri_(bf16x8 ahi, bf16x8 alo, bf16x8 bhi, bf16x8 blo, f32x4 acc) {
  acc = MFMA16(ahi, bhi, acc);
  acc = MFMA16(ahi, blo, acc);
  acc = MFMA16(alo, bhi, acc);
  return acc;
}

// ============================================================================
// Cooperative N-split kernel — R7 structure (best measured: 3066 us), with
// 1024-thread blocks: 16 waves = 8 col-tiles x 2 row-halves -> 4 waves/SIMD
// (was 2). Doubles TLP latency hiding; wave pairs (rh=0/1) load identical
// weight lines (L1 hit for the second). Sync structure IDENTICAL to R7:
// tid0 spins + barrier pairs (R9's per-wave spins regressed).
// ============================================================================
__global__ __launch_bounds__(1024, 4)
void lstm_coop(
    const int* __restrict__ x,
    const float* __restrict__ h0,
    const float* __restrict__ c0,
    const float* __restrict__ emb,
    const __hip_bfloat16* __restrict__ wsW,
    const float* __restrict__ fcW,
    const float* __restrict__ fcb,
    float* __restrict__ out)
{
  __shared__ __align__(16) __hip_bfloat16 h1s[2][2][RC][HP_];  // [buf][hi/lo][row][col]
  __shared__ __align__(16) __hip_bfloat16 h2s[2][RC][HP_];     // [hi/lo][row][col]
  __shared__ __align__(16) __hip_bfloat16 embs[2][V_][8];
  __shared__ unsigned short toks[RC][T_];
  __shared__ int slot_s;

  const int tid  = threadIdx.x;
  const int lane = tid & 63;
  const int wv   = tid >> 6;       // 16 waves
  const int m    = lane & 15;
  const int quad = lane >> 4;
  const int ct   = wv & 7;         // col-tile within the half
  const int rh   = wv >> 3;        // row half (0/1)
  const int rbase = rh * 16;
  const int jw   = ct * 16;
  const int lane32 = lane << 5;

  uint32_t* xch   = (uint32_t*)((char*)wsW + WSB_XCHG);
  uint32_t* flags = (uint32_t*)((char*)wsW + WSB_FLAGS);
  uint32_t* owner = flags + 512;
  uint32_t* cnt   = flags + 768;

  // ---- role assignment from physical XCD (CAS-probed bijection) ----
  if (tid == 0) {
    uint32_t xcd;
    asm volatile("s_getreg_b32 %0, hwreg(20, 0, 4)" : "=s"(xcd));  // HW_REG_XCC_ID
    xcd &= 7u;
    uint32_t rank = atomicAdd(&cnt[xcd], 1u) & 31u;
    int p = (int)((xcd * 32u + rank) & 255u);
    while (atomicCAS(&owner[p], 0u, 1u) != 0u) p = (p + 1) & 255;
    slot_s = p;
  }
  __syncthreads();
  const int slot = slot_s;
  const int vx   = slot >> 5;
  const int rank = slot & 31;
  const int half = vx >> 2;            // 0: cols 0..127, 1: cols 128..255
  const int tile = (vx & 3) * 32 + rank;   // 0..127 batch tile
  const int r0   = tile * RC;
  const int oh   = half ^ 1;
  const int colb = half * NH + jw + m;     // this lane's gate-col
  const int tcol = half * 8 + ct;          // global col-tile 0..15

  const char* wb    = (const char*)wsW;
  const char* pWhh0 = wb + WB_WHH0;
  const char* pWih1 = wb + WB_WIH1;
  const char* pWhh1 = wb + WB_WHH1;
  const char* pWih0 = wb + WB_WIH0;

  uint32_t* fl_own  = flags + half * NTILE + tile;              // tensor 0 (h1)
  uint32_t* fl_prt  = flags + oh   * NTILE + tile;
  uint32_t* fl_own1 = flags + 2 * NTILE + half * NTILE + tile;  // tensor 1 (h2)
  uint32_t* fl_prt1 = flags + 2 * NTILE + oh   * NTILE + tile;

  uint32_t* xo0 = xch + (((size_t)(0 * 2 + half) * NTILE + tile) * 2) * XCHG_U32;
  const uint32_t* xi0 = xch + (((size_t)(0 * 2 + oh) * NTILE + tile) * 2) * XCHG_U32;
  uint32_t* xo1 = xch + (((size_t)(1 * 2 + half) * NTILE + tile) * 2) * XCHG_U32;
  const uint32_t* xi1 = xch + (((size_t)(1 * 2 + oh) * NTILE + tile) * 2) * XCHG_U32;

  // ---------------- init ----------------
  if (tid < V_) {
#pragma unroll
    for (int j = 0; j < 8; ++j)
      split_(emb[tid * 8 + j], &embs[0][tid][j], &embs[1][tid][j]);
  }
  for (int i = tid; i < RC * T_; i += 1024) {
    int r = i / T_, tt = i - r * T_;
    int tok = x[(r0 + r) * T_ + tt];
    toks[r][tt] = (unsigned short)(tok < 0 ? 0 : (tok >= V_ ? V_ - 1 : tok));
  }
  for (int i = tid; i < RC * H_; i += 1024) {
    int r = i >> 8, cc = i & 255;
    split_(h0[(0 * B_ + r0 + r) * H_ + cc], &h1s[1][0][r][cc], &h1s[1][1][r][cc]);
    split_(h0[(1 * B_ + r0 + r) * H_ + cc], &h2s[0][r][cc],    &h2s[1][r][cc]);
  }
  f32x4 c1, c2;
#pragma unroll
  for (int r = 0; r < 4; ++r) {
    int row = r0 + rbase + quad * 4 + r;
    c1[r] = c0[(0 * B_ + row) * H_ + colb];
    c2[r] = c0[(1 * B_ + row) * H_ + colb];
  }

  bf16x8 zb;
#pragma unroll
  for (int j = 0; j < 8; ++j) zb[j] = (__bf16)0.0f;
  const f32x4 zf = {0.f, 0.f, 0.f, 0.f};

  __syncthreads();

  // ---------------- time loop ----------------
  for (int t = 0; t < T_; ++t) {
    const int p = t & 1, q = p ^ 1;

    // ===== layer 0 (own gate cols): e @ Wih0^T + h1_prev @ Whh0^T =====
    f32x4 acc[4];
    bf16x8 B0h[2][4], B0l[2][4];
#pragma unroll
    for (int g = 0; g < 4; ++g)
      ldfrag_(pWhh0 + ((size_t)((tcol * 8 + 0) * 4 + g) << 11) + lane32,
              &B0h[0][g], &B0l[0][g]);
    {
      bf16x8 eh = zb, el = zb;
      if (quad == 0) {
        int t0 = toks[rbase + m][t];
        eh = *(const bf16x8*)&embs[0][t0][0];
        el = *(const bf16x8*)&embs[1][t0][0];
      }
#pragma unroll
      for (int g = 0; g < 4; ++g) {
        bf16x8 Bh, Bl;   // unconditional: quad>0 lanes have A==0
        ldfrag_(pWih0 + (size_t)((tcol * 4 + g) * 512 + (m << 5)), &Bh, &Bl);
        acc[g] = tri_(eh, el, Bh, Bl, zf);
      }
    }
#pragma unroll
    for (int k = 0; k < 8; ++k) {
      const int kb = k & 1, kn = kb ^ 1;
      if (k < 7) {
#pragma unroll
        for (int g = 0; g < 4; ++g)
          ldfrag_(pWhh0 + ((size_t)((tcol * 8 + k + 1) * 4 + g) << 11) + lane32,
                  &B0h[kn][g], &B0l[kn][g]);
      }
      const int ko = k * 32 + quad * 8;
      bf16x8 Ah = *(const bf16x8*)&h1s[q][0][rbase + m][ko];
      bf16x8 Al = *(const bf16x8*)&h1s[q][1][rbase + m][ko];
#pragma unroll
      for (int g = 0; g < 4; ++g)
        acc[g] = tri_(Ah, Al, B0h[kb][g], B0l[kb][g], acc[g]);
    }

    // prefetch Whh1 k=0 (needed first in layer1-A)
    bf16x8 W1h[2][4], W1l[2][4];
#pragma unroll
    for (int g = 0; g < 4; ++g)
      ldfrag_(pWhh1 + ((size_t)((tcol * 8 + 0) * 4 + g) << 11) + lane32,
              &W1h[0][g], &W1l[0][g]);

    // gates 0 -> c1, h1; write own cols + exchange slot
    {
      uint32_t* xo = xo0 + (size_t)p * XCHG_U32;
#pragma unroll
      for (int r = 0; r < 4; ++r) {
        float ig = sigm_(acc[0][r]);
        float fg = sigm_(acc[1][r]);
        float gg = tanh_(acc[2][r]);
        float og = sigm_(acc[3][r]);
        float cn = fg * c1[r] + ig * gg;
        c1[r] = cn;
        float hv = og * tanh_(cn);
        int rr = rbase + quad * 4 + r;
        __hip_bfloat16 hi, lo;
        split_(hv, &hi, &lo);
        h1s[p][0][rr][colb] = hi;
        h1s[p][1][rr][colb] = lo;
        __hip_atomic_store(&xo[rr * NH + jw + m], pack2_(hi, lo),
                           __ATOMIC_RELAXED, __HIP_MEMORY_SCOPE_AGENT);
      }
    }
    __syncthreads();  // (1) own h1 stores drained before flag
    if (tid == 0) {
      __hip_atomic_store(fl_own, (uint32_t)(t + 1),
                         __ATOMIC_RELAXED, __HIP_MEMORY_SCOPE_AGENT);
      // cheap spin: partner h2(t-1) flag was set at end of partner's t-1
      while (__hip_atomic_load(fl_prt1, __ATOMIC_RELAXED,
                               __HIP_MEMORY_SCOPE_AGENT) < (uint32_t)t)
        __builtin_amdgcn_s_sleep(2);
    }
    __syncthreads();  // (2)
    if (t > 0) {  // assemble h2(t-1) partner half (u64 agent loads)
      const uint64_t* xj = (const uint64_t*)(xi1 + (size_t)q * XCHG_U32);
      for (int i = tid; i < RC * NH / 2; i += 1024) {
        uint64_t u = __hip_atomic_load(&xj[i], __ATOMIC_RELAXED, __HIP_MEMORY_SCOPE_AGENT);
        int row = i >> 6, c2v = (i & 63) * 2;
        uint32_t w0 = (uint32_t)u, w1 = (uint32_t)(u >> 32);
        h2s[0][row][oh * NH + c2v]     = ubf_((unsigned short)(w0 & 0xffffu));
        h2s[1][row][oh * NH + c2v]     = ubf_((unsigned short)(w0 >> 16));
        h2s[0][row][oh * NH + c2v + 1] = ubf_((unsigned short)(w1 & 0xffffu));
        h2s[1][row][oh * NH + c2v + 1] = ubf_((unsigned short)(w1 >> 16));
      }
    }
    __syncthreads();  // (3) h2(t-1) fully assembled

    // ===== layer1-A: h2_prev @ Whh1^T (independent of h1 exchange) =====
#pragma unroll
    for (int g = 0; g < 4; ++g) acc[g] = zf;
#pragma unroll
    for (int k = 0; k < 8; ++k) {
      const int kb = k & 1, kn = kb ^ 1;
      if (k < 7) {
#pragma unroll
        for (int g = 0; g < 4; ++g)
          ldfrag_(pWhh1 + ((size_t)((tcol * 8 + k + 1) * 4 + g) << 11) + lane32,
                  &W1h[kn][g], &W1l[kn][g]);
      }
      const int ko = k * 32 + quad * 8;
      bf16x8 Ch = *(const bf16x8*)&h2s[0][rbase + m][ko];
      bf16x8 Cl = *(const bf16x8*)&h2s[1][rbase + m][ko];
#pragma unroll
      for (int g = 0; g < 4; ++g)
        acc[g] = tri_(Ch, Cl, W1h[kb][g], W1l[kb][g], acc[g]);
    }

    // prefetch Wih1 k=0 (consumed after the h1 exchange)
    bf16x8 W2h[2][4], W2l[2][4];
#pragma unroll
    for (int g = 0; g < 4; ++g)
      ldfrag_(pWih1 + ((size_t)((tcol * 8 + 0) * 4 + g) << 11) + lane32,
              &W2h[0][g], &W2l[0][g]);

    // h1 spin — hidden behind layer1-A compute above
    if (tid == 0) {
      while (__hip_atomic_load(fl_prt, __ATOMIC_RELAXED,
                               __HIP_MEMORY_SCOPE_AGENT) < (uint32_t)(t + 1))
        __builtin_amdgcn_s_sleep(2);
    }
    __syncthreads();  // (4)
    {  // assemble h1(t) partner half
      const uint64_t* xi = (const uint64_t*)(xi0 + (size_t)p * XCHG_U32);
      for (int i = tid; i < RC * NH / 2; i += 1024) {
        uint64_t u = __hip_atomic_load(&xi[i], __ATOMIC_RELAXED, __HIP_MEMORY_SCOPE_AGENT);
        int row = i >> 6, c2v = (i & 63) * 2;
        uint32_t w0 = (uint32_t)u, w1 = (uint32_t)(u >> 32);
        h1s[p][0][row][oh * NH + c2v]     = ubf_((unsigned short)(w0 & 0xffffu));
        h1s[p][1][row][oh * NH + c2v]     = ubf_((unsigned short)(w0 >> 16));
        h1s[p][0][row][oh * NH + c2v + 1] = ubf_((unsigned short)(w1 & 0xffffu));
        h1s[p][1][row][oh * NH + c2v + 1] = ubf_((unsigned short)(w1 >> 16));
      }
    }
    __syncthreads();  // (5) h1(t) fully assembled; also fences layer1-A h2s reads

    // ===== layer1-B: h1_t @ Wih1^T (accumulate) =====
#pragma unroll
    for (int k = 0; k < 8; ++k) {
      const int kb = k & 1, kn = kb ^ 1;
      if (k < 7) {
#pragma unroll
        for (int g = 0; g < 4; ++g)
          ldfrag_(pWih1 + ((size_t)((tcol * 8 + k + 1) * 4 + g) << 11) + lane32,
                  &W2h[kn][g], &W2l[kn][g]);
      }
      const int ko = k * 32 + quad * 8;
      bf16x8 Ah = *(const bf16x8*)&h1s[p][0][rbase + m][ko];
      bf16x8 Al = *(const bf16x8*)&h1s[p][1][rbase + m][ko];
#pragma unroll
      for (int g = 0; g < 4; ++g)
        acc[g] = tri_(Ah, Al, W2h[kb][g], W2l[kb][g], acc[g]);
    }

    // gates 1 -> c2, h2; write own cols + exchange slot
    {
      uint32_t* xo = xo1 + (size_t)p * XCHG_U32;
#pragma unroll
      for (int r = 0; r < 4; ++r) {
        float ig = sigm_(acc[0][r]);
        float fg = sigm_(acc[1][r]);
        float gg = tanh_(acc[2][r]);
        float og = sigm_(acc[3][r]);
        float cn = fg * c2[r] + ig * gg;
        c2[r] = cn;
        float hv = og * tanh_(cn);
        int rr = rbase + quad * 4 + r;
        __hip_bfloat16 hi, lo;
        split_(hv, &hi, &lo);
        h2s[0][rr][colb] = hi;
        h2s[1][rr][colb] = lo;
        __hip_atomic_store(&xo[rr * NH + jw + m], pack2_(hi, lo),
                           __ATOMIC_RELAXED, __HIP_MEMORY_SCOPE_AGENT);
      }
    }
    __syncthreads();  // (6) drain xo1 stores
    if (tid == 0)
      __hip_atomic_store(fl_own1, (uint32_t)(t + 1),
                         __ATOMIC_RELAXED, __HIP_MEMORY_SCOPE_AGENT);
    // no spin here: partner's h2 is consumed at our t+1 (or epilogue)
  }

  // ---------------- final h2 exchange for logits/h_n ----------------
  if (tid == 0) {
    while (__hip_atomic_load(fl_prt1, __ATOMIC_RELAXED,
                             __HIP_MEMORY_SCOPE_AGENT) < (uint32_t)T_)
      __builtin_amdgcn_s_sleep(2);
  }
  __syncthreads();
  {
    const uint64_t* xj = (const uint64_t*)(xi1 + (size_t)((T_ - 1) & 1) * XCHG_U32);
    for (int i = tid; i < RC * NH / 2; i += 1024) {
      uint64_t u = __hip_atomic_load(&xj[i], __ATOMIC_RELAXED, __HIP_MEMORY_SCOPE_AGENT);
      int row = i >> 6, c2v = (i & 63) * 2;
      uint32_t w0 = (uint32_t)u, w1 = (uint32_t)(u >> 32);
      h2s[0][row][oh * NH + c2v]     = ubf_((unsigned short)(w0 & 0xffffu));
      h2s[1][row][oh * NH + c2v]     = ubf_((unsigned short)(w0 >> 16));
      h2s[0][row][oh * NH + c2v + 1] = ubf_((unsigned short)(w1 & 0xffffu));
      h2s[1][row][oh * NH + c2v + 1] = ubf_((unsigned short)(w1 >> 16));
    }
  }
  __syncthreads();

  // ---------------- outputs (fp32) ----------------
  const int pf = (T_ - 1) & 1;  // == 1

  for (int i = tid; i < RC * NH; i += 1024) {
    int r = i >> 7, c = i & (NH - 1), col = half * NH + c;
    out[OUT_HN + (0 * B_ + r0 + r) * H_ + col] =
        __bfloat162float(h1s[pf][0][r][col]) + __bfloat162float(h1s[pf][1][r][col]);
    out[OUT_HN + (1 * B_ + r0 + r) * H_ + col] =
        __bfloat162float(h2s[0][r][col]) + __bfloat162float(h2s[1][r][col]);
  }
#pragma unroll
  for (int r = 0; r < 4; ++r) {
    int row = r0 + rbase + quad * 4 + r;
    out[OUT_CN + row * H_ + colb]           = c1[r];
    out[OUT_CN + B_ * H_ + row * H_ + colb] = c2[r];
  }
  // logits: half 0 -> v in [0,40), half 1 -> v in [40,80); full h2 available
  for (int i = tid; i < RC * (V_ / 2); i += 1024) {
    int r = i / (V_ / 2), v = half * (V_ / 2) + i % (V_ / 2);
    const float* wp = fcW + v * H_;
    float s = fcb[v];
#pragma unroll 8
    for (int k = 0; k < H_; ++k) {
      float hk = __bfloat162float(h2s[0][r][k]) + __bfloat162float(h2s[1][r][k]);
      s += hk * wp[k];
    }
    out[(r0 + r) * V_ + v] = s;
  }
}

// ============================================================================
// Fallback (non-cooperative) kernel — used only when the workspace is too
// small for the exchange buffers. Uses the packed layout when available.
// ============================================================================
template<bool USE_WS>
__device__ __forceinline__ void loadB_(const char* wtb, int grp, int lane,
                                       const float* wf, int off,
                                       bf16x8* bhi, bf16x8* blo) {
  if (USE_WS) {
    const char* pp = wtb + ((size_t)grp << 11) + (lane << 5);
    *bhi = *(const bf16x8*)pp;
    *blo = *(const bf16x8*)(pp + 16);
  } else {
    f32x4 a = *(const f32x4*)(wf + off);
    f32x4 b = *(const f32x4*)(wf + off + 4);
#pragma unroll
    for (int j = 0; j < 4; ++j) {
      float w = a[j]; __bf16 h = (__bf16)w;
      (*bhi)[j] = h; (*blo)[j] = (__bf16)(w - (float)h);
    }
#pragma unroll
    for (int j = 0; j < 4; ++j) {
      float w = b[j]; __bf16 h = (__bf16)w;
      (*bhi)[4 + j] = h; (*blo)[4 + j] = (__bf16)(w - (float)h);
    }
  }
}

template<bool USE_WS>
__global__ __launch_bounds__(512, 2) void lstm_fused(
    const int* __restrict__ x,
    const float* __restrict__ h0,
    const float* __restrict__ c0,
    const float* __restrict__ emb,
    const __hip_bfloat16* __restrict__ wsW,
    const float* __restrict__ Wih0f,
    const float* __restrict__ Whh0f,
    const float* __restrict__ Wih1f,
    const float* __restrict__ Whh1f,
    const float* __restrict__ fcW,
    const float* __restrict__ fcb,
    float* __restrict__ out)
{
  __shared__ __align__(16) __hip_bfloat16 h1s[2][2][RF][HP_];
  __shared__ __align__(16) __hip_bfloat16 h2s[2][RF][HP_];
  __shared__ __align__(16) __hip_bfloat16 embs[2][V_][8];
  __shared__ __align__(16) __hip_bfloat16 es[2][RF][8];

  const int tid  = threadIdx.x;
  const int lane = tid & 63;
  const int wv   = tid >> 6;
  const int m    = lane & 15;
  const int quad = lane >> 4;
  const int jw   = wv * 32;
  const int r0   = blockIdx.x * RF;
  const char* wb = (const char*)wsW;

  if (tid < V_) {
#pragma unroll
    for (int j = 0; j < 8; ++j)
      split_(emb[tid * 8 + j], &embs[0][tid][j], &embs[1][tid][j]);
  }
  for (int i = tid; i < RF * H_; i += 512) {
    int r = i >> 8, cc = i & 255;
    split_(h0[(0 * B_ + r0 + r) * H_ + cc], &h1s[1][0][r][cc], &h1s[1][1][r][cc]);
    split_(h0[(1 * B_ + r0 + r) * H_ + cc], &h2s[0][r][cc],    &h2s[1][r][cc]);
  }
  f32x4 c1[2], c2[2];
#pragma unroll
  for (int ct = 0; ct < 2; ++ct)
#pragma unroll
    for (int r = 0; r < 4; ++r) {
      int row = r0 + quad * 4 + r;
      int col = jw + ct * 16 + m;
      c1[ct][r] = c0[(0 * B_ + row) * H_ + col];
      c2[ct][r] = c0[(1 * B_ + row) * H_ + col];
    }

  bf16x8 zb;
#pragma unroll
  for (int j = 0; j < 8; ++j) zb[j] = (__bf16)0.0f;
  const f32x4 zf = {0.f, 0.f, 0.f, 0.f};

  __syncthreads();

  for (int t = 0; t < T_; ++t) {
    const int p = t & 1, q = p ^ 1;

    if (tid < RF) {
      int tok = x[(r0 + tid) * T_ + t];
      tok = tok < 0 ? 0 : (tok >= V_ ? V_ - 1 : tok);
      *(bf16x8*)&es[0][tid][0] = *(const bf16x8*)&embs[0][tok][0];
      *(bf16x8*)&es[1][tid][0] = *(const bf16x8*)&embs[1][tok][0];
    }
    __syncthreads();

    f32x4 acc[8];
    {
      bf16x8 eh = zb, el = zb;
      if (quad == 0) {
        eh = *(const bf16x8*)&es[0][m][0];
        el = *(const bf16x8*)&es[1][m][0];
      }
#pragma unroll
      for (int g = 0; g < 4; ++g)
#pragma unroll
        for (int ct = 0; ct < 2; ++ct) {
          bf16x8 Bh = zb, Bl = zb;
          if (quad == 0) {
            if (USE_WS) {
              const char* pp = wb + WB_WIH0 +
                               (size_t)(((wv * 2 + ct) * 4 + g) * 512 + (m << 5));
              Bh = *(const bf16x8*)pp;
              Bl = *(const bf16x8*)(pp + 16);
            } else {
              const int off = (g * 256 + jw + ct * 16 + m) * 8;
              loadB_<false>(nullptr, 0, 0, Wih0f, off, &Bh, &Bl);
            }
          }
          acc[g * 2 + ct] = tri_(eh, el, Bh, Bl, zf);
        }
    }
#pragma unroll
    for (int k = 0; k < 8; ++k) {
      const int ko = k * 32 + quad * 8;
      bf16x8 Ah = *(const bf16x8*)&h1s[q][0][m][ko];
      bf16x8 Al = *(const bf16x8*)&h1s[q][1][m][ko];
#pragma unroll
      for (int g = 0; g < 4; ++g)
#pragma unroll
        for (int ct = 0; ct < 2; ++ct) {
          bf16x8 Bh, Bl;
          const int grp = ((wv * 2 + ct) * 8 + k) * 4 + g;
          const int off = (g * 256 + jw + ct * 16 + m) * H_ + ko;
          loadB_<USE_WS>(wb + WB_WHH0, grp, lane, Whh0f, off, &Bh, &Bl);
          acc[g * 2 + ct] = tri_(Ah, Al, Bh, Bl, acc[g * 2 + ct]);
        }
    }
#pragma unroll
    for (int ct = 0; ct < 2; ++ct)
#pragma unroll
      for (int r = 0; r < 4; ++r) {
        float ig = sigm_(acc[0 + ct][r]);
        float fg = sigm_(acc[2 + ct][r]);
        float gg = tanh_(acc[4 + ct][r]);
        float og = sigm_(acc[6 + ct][r]);
        float cn = fg * c1[ct][r] + ig * gg;
        c1[ct][r] = cn;
        float hv = og * tanh_(cn);
        int rr = quad * 4 + r, col = jw + ct * 16 + m;
        split_(hv, &h1s[p][0][rr][col], &h1s[p][1][rr][col]);
      }
    __syncthreads();

#pragma unroll
    for (int nt = 0; nt < 8; ++nt) acc[nt] = zf;
#pragma unroll
    for (int k = 0; k < 8; ++k) {
      const int ko = k * 32 + quad * 8;
      bf16x8 Ah = *(const bf16x8*)&h1s[p][0][m][ko];
      bf16x8 Al = *(const bf16x8*)&h1s[p][1][m][ko];
      bf16x8 Ch = *(const bf16x8*)&h2s[0][m][ko];
      bf16x8 Cl = *(const bf16x8*)&h2s[1][m][ko];
#pragma unroll
      for (int g = 0; g < 4; ++g)
#pragma unroll
        for (int ct = 0; ct < 2; ++ct) {
          const int grp = ((wv * 2 + ct) * 8 + k) * 4 + g;
          const int off = (g * 256 + jw + ct * 16 + m) * H_ + ko;
          bf16x8 Bh, Bl;
          loadB_<USE_WS>(wb + WB_WIH1, grp, lane, Wih1f, off, &Bh, &Bl);
          acc[g * 2 + ct] = tri_(Ah, Al, Bh, Bl, acc[g * 2 + ct]);
          loadB_<USE_WS>(wb + WB_WHH1, grp, lane, Whh1f, off, &Bh, &Bl);
          acc[g * 2 + ct] = tri_(Ch, Cl, Bh, Bl, acc[g * 2 + ct]);
        }
    }
    __syncthreads();

#pragma unroll
    for (int ct = 0; ct < 2; ++ct)
#pragma unroll
      for (int r = 0; r < 4; ++r) {
        float ig = sigm_(acc[0 + ct][r]);
        float fg = sigm_(acc[2 + ct][r]);
        float gg = tanh_(acc[4 + ct][r]);
        float og = sigm_(acc[6 + ct][r]);
        float cn = fg * c2[ct][r] + ig * gg;
        c2[ct][r] = cn;
        float hv = og * tanh_(cn);
        int rr = quad * 4 + r, col = jw + ct * 16 + m;
        split_(hv, &h2s[0][rr][col], &h2s[1][rr][col]);
      }
  }
  __syncthreads();

  const int pf = (T_ - 1) & 1;

  for (int i = tid; i < RF * H_; i += 512) {
    int r = i >> 8, cc = i & 255;
    out[OUT_HN + (0 * B_ + r0 + r) * H_ + cc] =
        __bfloat162float(h1s[pf][0][r][cc]) + __bfloat162float(h1s[pf][1][r][cc]);
    out[OUT_HN + (1 * B_ + r0 + r) * H_ + cc] =
        __bfloat162float(h2s[0][r][cc]) + __bfloat162float(h2s[1][r][cc]);
  }
#pragma unroll
  for (int ct = 0; ct < 2; ++ct)
#pragma unroll
    for (int r = 0; r < 4; ++r) {
      int row = r0 + quad * 4 + r;
      int col = jw + ct * 16 + m;
      out[OUT_CN + row * H_ + col]           = c1[ct][r];
      out[OUT_CN + B_ * H_ + row * H_ + col] = c2[ct][r];
    }
  for (int i = tid; i < RF * V_; i += 512) {
    int r = i / V_, v = i - r * V_;
    const float* wp = fcW + v * H_;
    float s = fcb[v];
#pragma unroll 8
    for (int k = 0; k < H_; ++k) {
      float hk = __bfloat162float(h2s[0][r][k]) + __bfloat162float(h2s[1][r][k]);
      s += hk * wp[k];
    }
    out[(r0 + r) * V_ + v] = s;
  }
}

extern "C" void kernel_launch(void* const* d_in, const int* in_sizes, int n_in,
                              void* d_out, int out_size, void* d_ws, size_t ws_size,
                              hipStream_t stream) {
  (void)in_sizes; (void)n_in; (void)out_size;
  const int*   x    = (const int*)d_in[0];
  const float* h0   = (const float*)d_in[1];
  const float* c0   = (const float*)d_in[2];
  const float* emb  = (const float*)d_in[3];
  const float* Wih0 = (const float*)d_in[4];
  const float* Whh0 = (const float*)d_in[5];
  const float* Wih1 = (const float*)d_in[6];
  const float* Whh1 = (const float*)d_in[7];
  const float* fcW  = (const float*)d_in[8];
  const float* fcb  = (const float*)d_in[9];
  float* outp = (float*)d_out;

  __hip_bfloat16* wsW = (__hip_bfloat16*)d_ws;

  if (ws_size >= WSB_TOTAL) {
    cvt_pair<<<(WS_PLANE + 255) / 256, 256, 0, stream>>>(Wih0, Whh0, Wih1, Whh1, wsW, 1);
    void* args[] = { (void*)&x, (void*)&h0, (void*)&c0, (void*)&emb, (void*)&wsW,
                     (void*)&fcW, (void*)&fcb, (void*)&outp };
    hipLaunchCooperativeKernel(reinterpret_cast<void*>(lstm_coop),
                               dim3(256), dim3(1024), args, 0, stream);
  } else if (ws_size >= WSB_XCHG) {
    cvt_pair<<<(WS_PLANE + 255) / 256, 256, 0, stream>>>(Wih0, Whh0, Wih1, Whh1, wsW, 0);
    lstm_fused<true><<<B_ / RF, 512, 0, stream>>>(
        x, h0, c0, emb, wsW, Wih0, Whh0, Wih1, Whh1, fcW, fcb, outp);
  } else {
    lstm_fused<false><<<B_ / RF, 512, 0, stream>>>(
        x, h0, c0, emb, wsW, Wih0, Whh0, Wih1, Whh1, fcW, fcb, outp);
  }
}

// Round 11
// 3063.245 us; speedup vs baseline: 1.7775x; 1.7775x over previous
//
#include <hip/hip_runtime.h>
#include <hip/hip_bf16.h>
#include <stdint.h>

typedef __bf16 bf16x8 __attribute__((ext_vector_type(8)));
typedef float  f32x4  __attribute__((ext_vector_type(4)));

#define MFMA16(a, b, c) __builtin_amdgcn_mfma_f32_16x16x32_bf16((a), (b), (c), 0, 0, 0)

namespace {
constexpr int T_   = 80;
constexpr int B_   = 4096;
constexpr int H_   = 256;
constexpr int HP_  = 264;   // padded LDS row stride
constexpr int V_   = 80;
constexpr int RF   = 16;    // fallback kernel: rows/block
constexpr int RC   = 32;    // coop kernel: rows per partner-pair tile
constexpr int NH   = 128;   // half of H (N-split width)
constexpr int NTILE = 128;  // batch tiles (B_/RC)
constexpr int OUT_HN = B_ * V_;
constexpr int OUT_CN = OUT_HN + 2 * B_ * H_;

// ---- WAVE-CONTIGUOUS weight layout (R6, proven) ----
// Fragment = 32 B = [hi bf16 x8][lo bf16 x8] for one (gate-row, 8 K-elems).
// K=256 tensors: fragment (coltile t=0..15, k=0..7, g=0..3, quad, m) covers
// W[g*256 + t*16 + m][k*32 + quad*8 .. +8] at byte
// base + ((t*8+k)*4+g)*2048 + (quad*16+m)*32  -> one 2 KB wave-block.
// Wih0 (K=8): (t, g, m) -> byte base + (t*4+g)*512 + m*32.
constexpr size_t WB_WHH0 = 0;                    // 1 MB
constexpr size_t WB_WIH1 = (size_t)1 << 20;      // 1 MB
constexpr size_t WB_WHH1 = (size_t)2 << 20;      // 1 MB
constexpr size_t WB_WIH0 = (size_t)3 << 20;      // 32 KB
constexpr int WS_PLANE = 794624;                 // total weight elems (grid size)
constexpr size_t WSB_XCHG  = 3178496;
constexpr size_t XCHG_U32  = (size_t)RC * NH;    // 4096 u32 per slot
constexpr size_t WSB_FLAGS = WSB_XCHG + (size_t)2 * 2 * NTILE * 2 * XCHG_U32 * 4;
constexpr int    CTRL_U32  = 512 + 256 + 8;
constexpr size_t WSB_TOTAL = WSB_FLAGS + (size_t)CTRL_U32 * 4;
}

__device__ __forceinline__ float sigm_(float x) { return 1.0f / (1.0f + __expf(-x)); }
__device__ __forceinline__ float tanh_(float x) {
  x = fminf(fmaxf(x, -15.f), 15.f);
  float e = __expf(2.f * x);
  return (e - 1.f) / (e + 1.f);
}

__device__ __forceinline__ void split_(float w, __hip_bfloat16* hi, __hip_bfloat16* lo) {
  __hip_bfloat16 h = __float2bfloat16(w);
  *hi = h;
  *lo = __float2bfloat16(w - __bfloat162float(h));
}

__device__ __forceinline__ uint32_t pack2_(__hip_bfloat16 hi, __hip_bfloat16 lo) {
  return (uint32_t)__builtin_bit_cast(unsigned short, hi) |
         ((uint32_t)__builtin_bit_cast(unsigned short, lo) << 16);
}
__device__ __forceinline__ __hip_bfloat16 ubf_(unsigned short v) {
  return __builtin_bit_cast(__hip_bfloat16, v);
}

// load one 32 B fragment (hi 16 B + lo 16 B, same cache line)
__device__ __forceinline__ void ldfrag_(const char* pp, bf16x8* h, bf16x8* l) {
  *h = *(const bf16x8*)pp;
  *l = *(const bf16x8*)(pp + 16);
}

// K=256 tensor: elem e (row-major [1024][256]) -> byte offset in packed layout
__device__ __forceinline__ size_t addrK256_(int e) {
  int row = e >> 8, kk = e & 255;
  int g = row >> 8, cb = row & 255, t = cb >> 4, m = cb & 15;
  int k = kk >> 5, quad = (kk >> 3) & 3, j = kk & 7;
  return (size_t)(((t * 8 + k) * 4 + g)) * 2048 + (size_t)((quad * 16 + m) * 32 + j * 2);
}

// weight pre-split + repack pass; optionally zero sync/ctrl
__global__ __launch_bounds__(256) void cvt_pair(
    const float* __restrict__ Wih0f, const float* __restrict__ Whh0f,
    const float* __restrict__ Wih1f, const float* __restrict__ Whh1f,
    __hip_bfloat16* __restrict__ ws, int zero_flags)
{
  if (zero_flags && blockIdx.x < 4) {
    uint32_t* fl = (uint32_t*)((char*)ws + WSB_FLAGS);
    int idx = blockIdx.x * 256 + threadIdx.x;
    if (idx < CTRL_U32) fl[idx] = 0u;
  }
  int i = blockIdx.x * 256 + threadIdx.x;
  if (i >= WS_PLANE) return;
  char* wb = (char*)ws;
  float v; size_t off;
  if (i < 262144) {
    v = Whh0f[i];            off = WB_WHH0 + addrK256_(i);
  } else if (i < 524288) {
    int e = i - 262144;
    v = Wih1f[e];            off = WB_WIH1 + addrK256_(e);
  } else if (i < 786432) {
    int e = i - 524288;
    v = Whh1f[e];            off = WB_WHH1 + addrK256_(e);
  } else {
    int e = i - 786432;      // Wih0: [1024][8]
    int row = e >> 3, j = e & 7;
    int g = row >> 8, cb = row & 255, t = cb >> 4, m = cb & 15;
    v = Wih0f[e];
    off = WB_WIH0 + (size_t)((t * 4 + g) * 512 + m * 32 + j * 2);
  }
  __hip_bfloat16 hi = __float2bfloat16(v);
  *(__hip_bfloat16*)(wb + off)      = hi;
  *(__hip_bfloat16*)(wb + off + 16) = __float2bfloat16(v - __bfloat162float(hi));
}

// acc += (Ahi+Alo)*(Bhi+Blo), dropping lo*lo (3 MFMAs)
__device__ __forceinline__ f32x4 tri_(bf16x8 ahi, bf16x8 alo, bf16x8 bhi, bf16x8 blo, f32x4 acc) {
  acc = MFMA16(ahi, bhi, acc);
  acc = MFMA16(ahi, blo, acc);
  acc = MFMA16(alo, bhi, acc);
  return acc;
}

// ============================================================================
// Cooperative N-split kernel, coalesced weight stream, sync-overlapped layer1.
// R7 structure — measured best (3066 us). R8 (4-way split), R9 (per-wave
// spins), R10 (1024-thread) all regressed; this is the verbatim revert.
// Per step: layer0 -> set h1 flag + cheap h2(t-1) spin -> layer1-A (Whh1 x h2,
// independent of h1 exchange) -> h1 spin (hidden behind A) -> layer1-B
// (Wih1 x h1) -> gates -> h2 store (no spin).
// ============================================================================
__global__ __attribute__((amdgpu_waves_per_eu(2, 2))) __launch_bounds__(512)
void lstm_coop(
    const int* __restrict__ x,
    const float* __restrict__ h0,
    const float* __restrict__ c0,
    const float* __restrict__ emb,
    const __hip_bfloat16* __restrict__ wsW,
    const float* __restrict__ fcW,
    const float* __restrict__ fcb,
    float* __restrict__ out)
{
  __shared__ __align__(16) __hip_bfloat16 h1s[2][2][RC][HP_];  // [buf][hi/lo][row][col]
  __shared__ __align__(16) __hip_bfloat16 h2s[2][RC][HP_];     // [hi/lo][row][col]
  __shared__ __align__(16) __hip_bfloat16 embs[2][V_][8];
  __shared__ unsigned short toks[RC][T_];
  __shared__ int slot_s;

  const int tid  = threadIdx.x;
  const int lane = tid & 63;
  const int wv   = tid >> 6;       // 8 waves
  const int m    = lane & 15;
  const int quad = lane >> 4;
  const int jw   = wv * 16;        // 16-col tile per wave within the half
  const int lane32 = lane << 5;

  uint32_t* xch   = (uint32_t*)((char*)wsW + WSB_XCHG);
  uint32_t* flags = (uint32_t*)((char*)wsW + WSB_FLAGS);
  uint32_t* owner = flags + 512;
  uint32_t* cnt   = flags + 768;

  // ---- role assignment from physical XCD (CAS-probed bijection) ----
  if (tid == 0) {
    uint32_t xcd;
    asm volatile("s_getreg_b32 %0, hwreg(20, 0, 4)" : "=s"(xcd));  // HW_REG_XCC_ID
    xcd &= 7u;
    uint32_t rank = atomicAdd(&cnt[xcd], 1u) & 31u;
    int p = (int)((xcd * 32u + rank) & 255u);
    while (atomicCAS(&owner[p], 0u, 1u) != 0u) p = (p + 1) & 255;
    slot_s = p;
  }
  __syncthreads();
  const int slot = slot_s;
  const int vx   = slot >> 5;
  const int rank = slot & 31;
  const int half = vx >> 2;            // 0: cols 0..127, 1: cols 128..255
  const int tile = (vx & 3) * 32 + rank;   // 0..127 batch tile
  const int r0   = tile * RC;
  const int oh   = half ^ 1;
  const int colb = half * NH + jw + m;     // this lane's gate-col
  const int tcol = half * 8 + wv;          // global col-tile 0..15

  const char* wb    = (const char*)wsW;
  const char* pWhh0 = wb + WB_WHH0;
  const char* pWih1 = wb + WB_WIH1;
  const char* pWhh1 = wb + WB_WHH1;
  const char* pWih0 = wb + WB_WIH0;

  uint32_t* fl_own  = flags + half * NTILE + tile;              // tensor 0 (h1)
  uint32_t* fl_prt  = flags + oh   * NTILE + tile;
  uint32_t* fl_own1 = flags + 2 * NTILE + half * NTILE + tile;  // tensor 1 (h2)
  uint32_t* fl_prt1 = flags + 2 * NTILE + oh   * NTILE + tile;

  uint32_t* xo0 = xch + (((size_t)(0 * 2 + half) * NTILE + tile) * 2) * XCHG_U32;
  const uint32_t* xi0 = xch + (((size_t)(0 * 2 + oh) * NTILE + tile) * 2) * XCHG_U32;
  uint32_t* xo1 = xch + (((size_t)(1 * 2 + half) * NTILE + tile) * 2) * XCHG_U32;
  const uint32_t* xi1 = xch + (((size_t)(1 * 2 + oh) * NTILE + tile) * 2) * XCHG_U32;

  // ---------------- init ----------------
  if (tid < V_) {
#pragma unroll
    for (int j = 0; j < 8; ++j)
      split_(emb[tid * 8 + j], &embs[0][tid][j], &embs[1][tid][j]);
  }
  for (int i = tid; i < RC * T_; i += 512) {
    int r = i / T_, tt = i - r * T_;
    int tok = x[(r0 + r) * T_ + tt];
    toks[r][tt] = (unsigned short)(tok < 0 ? 0 : (tok >= V_ ? V_ - 1 : tok));
  }
  for (int i = tid; i < RC * H_; i += 512) {
    int r = i >> 8, cc = i & 255;
    split_(h0[(0 * B_ + r0 + r) * H_ + cc], &h1s[1][0][r][cc], &h1s[1][1][r][cc]);
    split_(h0[(1 * B_ + r0 + r) * H_ + cc], &h2s[0][r][cc],    &h2s[1][r][cc]);
  }
  f32x4 c1[2], c2[2];
#pragma unroll
  for (int mt = 0; mt < 2; ++mt)
#pragma unroll
    for (int r = 0; r < 4; ++r) {
      int row = r0 + mt * 16 + quad * 4 + r;
      c1[mt][r] = c0[(0 * B_ + row) * H_ + colb];
      c2[mt][r] = c0[(1 * B_ + row) * H_ + colb];
    }

  bf16x8 zb;
#pragma unroll
  for (int j = 0; j < 8; ++j) zb[j] = (__bf16)0.0f;
  const f32x4 zf = {0.f, 0.f, 0.f, 0.f};

  __syncthreads();

  // ---------------- time loop ----------------
  for (int t = 0; t < T_; ++t) {
    const int p = t & 1, q = p ^ 1;

    // ===== layer 0 (own gate cols): e @ Wih0^T + h1_prev @ Whh0^T =====
    f32x4 acc[2][4];
    bf16x8 B0h[2][4], B0l[2][4];
#pragma unroll
    for (int g = 0; g < 4; ++g)   // preload Whh0 k=0 (contiguous 2 KB blocks)
      ldfrag_(pWhh0 + ((size_t)((tcol * 8 + 0) * 4 + g) << 11) + lane32,
              &B0h[0][g], &B0l[0][g]);
    {
      bf16x8 eh0 = zb, el0 = zb, eh1 = zb, el1 = zb;
      if (quad == 0) {
        int t0 = toks[m][t], t1 = toks[16 + m][t];
        eh0 = *(const bf16x8*)&embs[0][t0][0]; el0 = *(const bf16x8*)&embs[1][t0][0];
        eh1 = *(const bf16x8*)&embs[0][t1][0]; el1 = *(const bf16x8*)&embs[1][t1][0];
      }
#pragma unroll
      for (int g = 0; g < 4; ++g) {
        // B load unconditional: quad>0 lanes have A==0 so their B value is moot
        bf16x8 Bh, Bl;
        ldfrag_(pWih0 + (size_t)((tcol * 4 + g) * 512 + (m << 5)), &Bh, &Bl);
        acc[0][g] = tri_(eh0, el0, Bh, Bl, zf);
        acc[1][g] = tri_(eh1, el1, Bh, Bl, zf);
      }
    }
#pragma unroll
    for (int k = 0; k < 8; ++k) {
      const int kb = k & 1, kn = kb ^ 1;
      if (k < 7) {
#pragma unroll
        for (int g = 0; g < 4; ++g)
          ldfrag_(pWhh0 + ((size_t)((tcol * 8 + k + 1) * 4 + g) << 11) + lane32,
                  &B0h[kn][g], &B0l[kn][g]);
      }
      const int ko = k * 32 + quad * 8;
      bf16x8 Ah0 = *(const bf16x8*)&h1s[q][0][m][ko];
      bf16x8 Al0 = *(const bf16x8*)&h1s[q][1][m][ko];
      bf16x8 Ah1 = *(const bf16x8*)&h1s[q][0][16 + m][ko];
      bf16x8 Al1 = *(const bf16x8*)&h1s[q][1][16 + m][ko];
#pragma unroll
      for (int g = 0; g < 4; ++g) {
        acc[0][g] = tri_(Ah0, Al0, B0h[kb][g], B0l[kb][g], acc[0][g]);
        acc[1][g] = tri_(Ah1, Al1, B0h[kb][g], B0l[kb][g], acc[1][g]);
      }
    }

    // prefetch Whh1 k=0 (needed first in layer1-A, independent of exchanges)
    bf16x8 W1h[2][4], W1l[2][4];
#pragma unroll
    for (int g = 0; g < 4; ++g)
      ldfrag_(pWhh1 + ((size_t)((tcol * 8 + 0) * 4 + g) << 11) + lane32,
              &W1h[0][g], &W1l[0][g]);

    // gates 0 -> c1, h1; write own cols + exchange slot
    {
      uint32_t* xo = xo0 + (size_t)p * XCHG_U32;
#pragma unroll
      for (int mt = 0; mt < 2; ++mt)
#pragma unroll
        for (int r = 0; r < 4; ++r) {
          float ig = sigm_(acc[mt][0][r]);
          float fg = sigm_(acc[mt][1][r]);
          float gg = tanh_(acc[mt][2][r]);
          float og = sigm_(acc[mt][3][r]);
          float cn = fg * c1[mt][r] + ig * gg;
          c1[mt][r] = cn;
          float hv = og * tanh_(cn);
          int rr = mt * 16 + quad * 4 + r;
          __hip_bfloat16 hi, lo;
          split_(hv, &hi, &lo);
          h1s[p][0][rr][colb] = hi;
          h1s[p][1][rr][colb] = lo;
          __hip_atomic_store(&xo[rr * NH + jw + m], pack2_(hi, lo),
                             __ATOMIC_RELAXED, __HIP_MEMORY_SCOPE_AGENT);
        }
    }
    __syncthreads();  // (1) own h1 stores drained before flag
    if (tid == 0) {
      __hip_atomic_store(fl_own, (uint32_t)(t + 1),
                         __ATOMIC_RELAXED, __HIP_MEMORY_SCOPE_AGENT);
      // cheap spin: partner h2(t-1) flag was set at end of partner's t-1
      while (__hip_atomic_load(fl_prt1, __ATOMIC_RELAXED,
                               __HIP_MEMORY_SCOPE_AGENT) < (uint32_t)t)
        __builtin_amdgcn_s_sleep(2);
    }
    __syncthreads();  // (2)
    if (t > 0) {  // assemble h2(t-1) partner half (u64 agent loads)
      const uint64_t* xj = (const uint64_t*)(xi1 + (size_t)q * XCHG_U32);
      for (int i = tid; i < RC * NH / 2; i += 512) {
        uint64_t u = __hip_atomic_load(&xj[i], __ATOMIC_RELAXED, __HIP_MEMORY_SCOPE_AGENT);
        int row = i >> 6, c2 = (i & 63) * 2;
        uint32_t w0 = (uint32_t)u, w1 = (uint32_t)(u >> 32);
        h2s[0][row][oh * NH + c2]     = ubf_((unsigned short)(w0 & 0xffffu));
        h2s[1][row][oh * NH + c2]     = ubf_((unsigned short)(w0 >> 16));
        h2s[0][row][oh * NH + c2 + 1] = ubf_((unsigned short)(w1 & 0xffffu));
        h2s[1][row][oh * NH + c2 + 1] = ubf_((unsigned short)(w1 >> 16));
      }
    }
    __syncthreads();  // (3) h2(t-1) fully assembled

    // ===== layer1-A: h2_prev @ Whh1^T (independent of h1 exchange) =====
#pragma unroll
    for (int mt = 0; mt < 2; ++mt)
#pragma unroll
      for (int g = 0; g < 4; ++g) acc[mt][g] = zf;
#pragma unroll
    for (int k = 0; k < 8; ++k) {
      const int kb = k & 1, kn = kb ^ 1;
      if (k < 7) {
#pragma unroll
        for (int g = 0; g < 4; ++g)
          ldfrag_(pWhh1 + ((size_t)((tcol * 8 + k + 1) * 4 + g) << 11) + lane32,
                  &W1h[kn][g], &W1l[kn][g]);
      }
      const int ko = k * 32 + quad * 8;
      bf16x8 Ch0 = *(const bf16x8*)&h2s[0][m][ko];
      bf16x8 Cl0 = *(const bf16x8*)&h2s[1][m][ko];
      bf16x8 Ch1 = *(const bf16x8*)&h2s[0][16 + m][ko];
      bf16x8 Cl1 = *(const bf16x8*)&h2s[1][16 + m][ko];
#pragma unroll
      for (int g = 0; g < 4; ++g) {
        acc[0][g] = tri_(Ch0, Cl0, W1h[kb][g], W1l[kb][g], acc[0][g]);
        acc[1][g] = tri_(Ch1, Cl1, W1h[kb][g], W1l[kb][g], acc[1][g]);
      }
    }

    // prefetch Wih1 k=0 (consumed after the h1 exchange)
    bf16x8 W2h[2][4], W2l[2][4];
#pragma unroll
    for (int g = 0; g < 4; ++g)
      ldfrag_(pWih1 + ((size_t)((tcol * 8 + 0) * 4 + g) << 11) + lane32,
              &W2h[0][g], &W2l[0][g]);

    // h1 spin — hidden behind layer1-A compute above
    if (tid == 0) {
      while (__hip_atomic_load(fl_prt, __ATOMIC_RELAXED,
                               __HIP_MEMORY_SCOPE_AGENT) < (uint32_t)(t + 1))
        __builtin_amdgcn_s_sleep(2);
    }
    __syncthreads();  // (4)
    {  // assemble h1(t) partner half
      const uint64_t* xi = (const uint64_t*)(xi0 + (size_t)p * XCHG_U32);
      for (int i = tid; i < RC * NH / 2; i += 512) {
        uint64_t u = __hip_atomic_load(&xi[i], __ATOMIC_RELAXED, __HIP_MEMORY_SCOPE_AGENT);
        int row = i >> 6, c2 = (i & 63) * 2;
        uint32_t w0 = (uint32_t)u, w1 = (uint32_t)(u >> 32);
        h1s[p][0][row][oh * NH + c2]     = ubf_((unsigned short)(w0 & 0xffffu));
        h1s[p][1][row][oh * NH + c2]     = ubf_((unsigned short)(w0 >> 16));
        h1s[p][0][row][oh * NH + c2 + 1] = ubf_((unsigned short)(w1 & 0xffffu));
        h1s[p][1][row][oh * NH + c2 + 1] = ubf_((unsigned short)(w1 >> 16));
      }
    }
    __syncthreads();  // (5) h1(t) fully assembled; also fences layer1-A h2s reads

    // ===== layer1-B: h1_t @ Wih1^T (accumulate) =====
#pragma unroll
    for (int k = 0; k < 8; ++k) {
      const int kb = k & 1, kn = kb ^ 1;
      if (k < 7) {
#pragma unroll
        for (int g = 0; g < 4; ++g)
          ldfrag_(pWih1 + ((size_t)((tcol * 8 + k + 1) * 4 + g) << 11) + lane32,
                  &W2h[kn][g], &W2l[kn][g]);
      }
      const int ko = k * 32 + quad * 8;
      bf16x8 Ah0 = *(const bf16x8*)&h1s[p][0][m][ko];
      bf16x8 Al0 = *(const bf16x8*)&h1s[p][1][m][ko];
      bf16x8 Ah1 = *(const bf16x8*)&h1s[p][0][16 + m][ko];
      bf16x8 Al1 = *(const bf16x8*)&h1s[p][1][16 + m][ko];
#pragma unroll
      for (int g = 0; g < 4; ++g) {
        acc[0][g] = tri_(Ah0, Al0, W2h[kb][g], W2l[kb][g], acc[0][g]);
        acc[1][g] = tri_(Ah1, Al1, W2h[kb][g], W2l[kb][g], acc[1][g]);
      }
    }

    // gates 1 -> c2, h2; write own cols + exchange slot
    {
      uint32_t* xo = xo1 + (size_t)p * XCHG_U32;
#pragma unroll
      for (int mt = 0; mt < 2; ++mt)
#pragma unroll
        for (int r = 0; r < 4; ++r) {
          float ig = sigm_(acc[mt][0][r]);
          float fg = sigm_(acc[mt][1][r]);
          float gg = tanh_(acc[mt][2][r]);
          float og = sigm_(acc[mt][3][r]);
          float cn = fg * c2[mt][r] + ig * gg;
          c2[mt][r] = cn;
          float hv = og * tanh_(cn);
          int rr = mt * 16 + quad * 4 + r;
          __hip_bfloat16 hi, lo;
          split_(hv, &hi, &lo);
          h2s[0][rr][colb] = hi;
          h2s[1][rr][colb] = lo;
          __hip_atomic_store(&xo[rr * NH + jw + m], pack2_(hi, lo),
                             __ATOMIC_RELAXED, __HIP_MEMORY_SCOPE_AGENT);
        }
    }
    __syncthreads();  // (6) drain xo1 stores
    if (tid == 0)
      __hip_atomic_store(fl_own1, (uint32_t)(t + 1),
                         __ATOMIC_RELAXED, __HIP_MEMORY_SCOPE_AGENT);
    // no spin here: partner's h2 is consumed at our t+1 (or epilogue)
  }

  // ---------------- final h2 exchange for logits/h_n ----------------
  if (tid == 0) {
    while (__hip_atomic_load(fl_prt1, __ATOMIC_RELAXED,
                             __HIP_MEMORY_SCOPE_AGENT) < (uint32_t)T_)
      __builtin_amdgcn_s_sleep(2);
  }
  __syncthreads();
  {
    const uint64_t* xj = (const uint64_t*)(xi1 + (size_t)((T_ - 1) & 1) * XCHG_U32);
    for (int i = tid; i < RC * NH / 2; i += 512) {
      uint64_t u = __hip_atomic_load(&xj[i], __ATOMIC_RELAXED, __HIP_MEMORY_SCOPE_AGENT);
      int row = i >> 6, c2 = (i & 63) * 2;
      uint32_t w0 = (uint32_t)u, w1 = (uint32_t)(u >> 32);
      h2s[0][row][oh * NH + c2]     = ubf_((unsigned short)(w0 & 0xffffu));
      h2s[1][row][oh * NH + c2]     = ubf_((unsigned short)(w0 >> 16));
      h2s[0][row][oh * NH + c2 + 1] = ubf_((unsigned short)(w1 & 0xffffu));
      h2s[1][row][oh * NH + c2 + 1] = ubf_((unsigned short)(w1 >> 16));
    }
  }
  __syncthreads();

  // ---------------- outputs (fp32) ----------------
  const int pf = (T_ - 1) & 1;  // == 1

  for (int i = tid; i < RC * NH; i += 512) {
    int r = i >> 7, c = i & (NH - 1), col = half * NH + c;
    out[OUT_HN + (0 * B_ + r0 + r) * H_ + col] =
        __bfloat162float(h1s[pf][0][r][col]) + __bfloat162float(h1s[pf][1][r][col]);
    out[OUT_HN + (1 * B_ + r0 + r) * H_ + col] =
        __bfloat162float(h2s[0][r][col]) + __bfloat162float(h2s[1][r][col]);
  }
#pragma unroll
  for (int mt = 0; mt < 2; ++mt)
#pragma unroll
    for (int r = 0; r < 4; ++r) {
      int row = r0 + mt * 16 + quad * 4 + r;
      out[OUT_CN + row * H_ + colb]           = c1[mt][r];
      out[OUT_CN + B_ * H_ + row * H_ + colb] = c2[mt][r];
    }
  // logits: half 0 -> v in [0,40), half 1 -> v in [40,80); full h2 available
  for (int i = tid; i < RC * (V_ / 2); i += 512) {
    int r = i / (V_ / 2), v = half * (V_ / 2) + i % (V_ / 2);
    const float* wp = fcW + v * H_;
    float s = fcb[v];
#pragma unroll 8
    for (int k = 0; k < H_; ++k) {
      float hk = __bfloat162float(h2s[0][r][k]) + __bfloat162float(h2s[1][r][k]);
      s += hk * wp[k];
    }
    out[(r0 + r) * V_ + v] = s;
  }
}

// ============================================================================
// Fallback (non-cooperative) kernel — used only when the workspace is too
// small for the exchange buffers. Uses the packed layout when available.
// ============================================================================
template<bool USE_WS>
__device__ __forceinline__ void loadB_(const char* wtb, int grp, int lane,
                                       const float* wf, int off,
                                       bf16x8* bhi, bf16x8* blo) {
  if (USE_WS) {
    const char* pp = wtb + ((size_t)grp << 11) + (lane << 5);
    *bhi = *(const bf16x8*)pp;
    *blo = *(const bf16x8*)(pp + 16);
  } else {
    f32x4 a = *(const f32x4*)(wf + off);
    f32x4 b = *(const f32x4*)(wf + off + 4);
#pragma unroll
    for (int j = 0; j < 4; ++j) {
      float w = a[j]; __bf16 h = (__bf16)w;
      (*bhi)[j] = h; (*blo)[j] = (__bf16)(w - (float)h);
    }
#pragma unroll
    for (int j = 0; j < 4; ++j) {
      float w = b[j]; __bf16 h = (__bf16)w;
      (*bhi)[4 + j] = h; (*blo)[4 + j] = (__bf16)(w - (float)h);
    }
  }
}

template<bool USE_WS>
__global__ __launch_bounds__(512, 2) void lstm_fused(
    const int* __restrict__ x,
    const float* __restrict__ h0,
    const float* __restrict__ c0,
    const float* __restrict__ emb,
    const __hip_bfloat16* __restrict__ wsW,
    const float* __restrict__ Wih0f,
    const float* __restrict__ Whh0f,
    const float* __restrict__ Wih1f,
    const float* __restrict__ Whh1f,
    const float* __restrict__ fcW,
    const float* __restrict__ fcb,
    float* __restrict__ out)
{
  __shared__ __align__(16) __hip_bfloat16 h1s[2][2][RF][HP_];
  __shared__ __align__(16) __hip_bfloat16 h2s[2][RF][HP_];
  __shared__ __align__(16) __hip_bfloat16 embs[2][V_][8];
  __shared__ __align__(16) __hip_bfloat16 es[2][RF][8];

  const int tid  = threadIdx.x;
  const int lane = tid & 63;
  const int wv   = tid >> 6;
  const int m    = lane & 15;
  const int quad = lane >> 4;
  const int jw   = wv * 32;
  const int r0   = blockIdx.x * RF;
  const char* wb = (const char*)wsW;

  if (tid < V_) {
#pragma unroll
    for (int j = 0; j < 8; ++j)
      split_(emb[tid * 8 + j], &embs[0][tid][j], &embs[1][tid][j]);
  }
  for (int i = tid; i < RF * H_; i += 512) {
    int r = i >> 8, cc = i & 255;
    split_(h0[(0 * B_ + r0 + r) * H_ + cc], &h1s[1][0][r][cc], &h1s[1][1][r][cc]);
    split_(h0[(1 * B_ + r0 + r) * H_ + cc], &h2s[0][r][cc],    &h2s[1][r][cc]);
  }
  f32x4 c1[2], c2[2];
#pragma unroll
  for (int ct = 0; ct < 2; ++ct)
#pragma unroll
    for (int r = 0; r < 4; ++r) {
      int row = r0 + quad * 4 + r;
      int col = jw + ct * 16 + m;
      c1[ct][r] = c0[(0 * B_ + row) * H_ + col];
      c2[ct][r] = c0[(1 * B_ + row) * H_ + col];
    }

  bf16x8 zb;
#pragma unroll
  for (int j = 0; j < 8; ++j) zb[j] = (__bf16)0.0f;
  const f32x4 zf = {0.f, 0.f, 0.f, 0.f};

  __syncthreads();

  for (int t = 0; t < T_; ++t) {
    const int p = t & 1, q = p ^ 1;

    if (tid < RF) {
      int tok = x[(r0 + tid) * T_ + t];
      tok = tok < 0 ? 0 : (tok >= V_ ? V_ - 1 : tok);
      *(bf16x8*)&es[0][tid][0] = *(const bf16x8*)&embs[0][tok][0];
      *(bf16x8*)&es[1][tid][0] = *(const bf16x8*)&embs[1][tok][0];
    }
    __syncthreads();

    f32x4 acc[8];
    {
      bf16x8 eh = zb, el = zb;
      if (quad == 0) {
        eh = *(const bf16x8*)&es[0][m][0];
        el = *(const bf16x8*)&es[1][m][0];
      }
#pragma unroll
      for (int g = 0; g < 4; ++g)
#pragma unroll
        for (int ct = 0; ct < 2; ++ct) {
          bf16x8 Bh = zb, Bl = zb;
          if (quad == 0) {
            if (USE_WS) {
              const char* pp = wb + WB_WIH0 +
                               (size_t)(((wv * 2 + ct) * 4 + g) * 512 + (m << 5));
              Bh = *(const bf16x8*)pp;
              Bl = *(const bf16x8*)(pp + 16);
            } else {
              const int off = (g * 256 + jw + ct * 16 + m) * 8;
              loadB_<false>(nullptr, 0, 0, Wih0f, off, &Bh, &Bl);
            }
          }
          acc[g * 2 + ct] = tri_(eh, el, Bh, Bl, zf);
        }
    }
#pragma unroll
    for (int k = 0; k < 8; ++k) {
      const int ko = k * 32 + quad * 8;
      bf16x8 Ah = *(const bf16x8*)&h1s[q][0][m][ko];
      bf16x8 Al = *(const bf16x8*)&h1s[q][1][m][ko];
#pragma unroll
      for (int g = 0; g < 4; ++g)
#pragma unroll
        for (int ct = 0; ct < 2; ++ct) {
          bf16x8 Bh, Bl;
          const int grp = ((wv * 2 + ct) * 8 + k) * 4 + g;
          const int off = (g * 256 + jw + ct * 16 + m) * H_ + ko;
          loadB_<USE_WS>(wb + WB_WHH0, grp, lane, Whh0f, off, &Bh, &Bl);
          acc[g * 2 + ct] = tri_(Ah, Al, Bh, Bl, acc[g * 2 + ct]);
        }
    }
#pragma unroll
    for (int ct = 0; ct < 2; ++ct)
#pragma unroll
      for (int r = 0; r < 4; ++r) {
        float ig = sigm_(acc[0 + ct][r]);
        float fg = sigm_(acc[2 + ct][r]);
        float gg = tanh_(acc[4 + ct][r]);
        float og = sigm_(acc[6 + ct][r]);
        float cn = fg * c1[ct][r] + ig * gg;
        c1[ct][r] = cn;
        float hv = og * tanh_(cn);
        int rr = quad * 4 + r, col = jw + ct * 16 + m;
        split_(hv, &h1s[p][0][rr][col], &h1s[p][1][rr][col]);
      }
    __syncthreads();

#pragma unroll
    for (int nt = 0; nt < 8; ++nt) acc[nt] = zf;
#pragma unroll
    for (int k = 0; k < 8; ++k) {
      const int ko = k * 32 + quad * 8;
      bf16x8 Ah = *(const bf16x8*)&h1s[p][0][m][ko];
      bf16x8 Al = *(const bf16x8*)&h1s[p][1][m][ko];
      bf16x8 Ch = *(const bf16x8*)&h2s[0][m][ko];
      bf16x8 Cl = *(const bf16x8*)&h2s[1][m][ko];
#pragma unroll
      for (int g = 0; g < 4; ++g)
#pragma unroll
        for (int ct = 0; ct < 2; ++ct) {
          const int grp = ((wv * 2 + ct) * 8 + k) * 4 + g;
          const int off = (g * 256 + jw + ct * 16 + m) * H_ + ko;
          bf16x8 Bh, Bl;
          loadB_<USE_WS>(wb + WB_WIH1, grp, lane, Wih1f, off, &Bh, &Bl);
          acc[g * 2 + ct] = tri_(Ah, Al, Bh, Bl, acc[g * 2 + ct]);
          loadB_<USE_WS>(wb + WB_WHH1, grp, lane, Whh1f, off, &Bh, &Bl);
          acc[g * 2 + ct] = tri_(Ch, Cl, Bh, Bl, acc[g * 2 + ct]);
        }
    }
    __syncthreads();

#pragma unroll
    for (int ct = 0; ct < 2; ++ct)
#pragma unroll
      for (int r = 0; r < 4; ++r) {
        float ig = sigm_(acc[0 + ct][r]);
        float fg = sigm_(acc[2 + ct][r]);
        float gg = tanh_(acc[4 + ct][r]);
        float og = sigm_(acc[6 + ct][r]);
        float cn = fg * c2[ct][r] + ig * gg;
        c2[ct][r] = cn;
        float hv = og * tanh_(cn);
        int rr = quad * 4 + r, col = jw + ct * 16 + m;
        split_(hv, &h2s[0][rr][col], &h2s[1][rr][col]);
      }
  }
  __syncthreads();

  const int pf = (T_ - 1) & 1;

  for (int i = tid; i < RF * H_; i += 512) {
    int r = i >> 8, cc = i & 255;
    out[OUT_HN + (0 * B_ + r0 + r) * H_ + cc] =
        __bfloat162float(h1s[pf][0][r][cc]) + __bfloat162float(h1s[pf][1][r][cc]);
    out[OUT_HN + (1 * B_ + r0 + r) * H_ + cc] =
        __bfloat162float(h2s[0][r][cc]) + __bfloat162float(h2s[1][r][cc]);
  }
#pragma unroll
  for (int ct = 0; ct < 2; ++ct)
#pragma unroll
    for (int r = 0; r < 4; ++r) {
      int row = r0 + quad * 4 + r;
      int col = jw + ct * 16 + m;
      out[OUT_CN + row * H_ + col]           = c1[ct][r];
      out[OUT_CN + B_ * H_ + row * H_ + col] = c2[ct][r];
    }
  for (int i = tid; i < RF * V_; i += 512) {
    int r = i / V_, v = i - r * V_;
    const float* wp = fcW + v * H_;
    float s = fcb[v];
#pragma unroll 8
    for (int k = 0; k < H_; ++k) {
      float hk = __bfloat162float(h2s[0][r][k]) + __bfloat162float(h2s[1][r][k]);
      s += hk * wp[k];
    }
    out[(r0 + r) * V_ + v] = s;
  }
}

extern "C" void kernel_launch(void* const* d_in, const int* in_sizes, int n_in,
                              void* d_out, int out_size, void* d_ws, size_t ws_size,
                              hipStream_t stream) {
  (void)in_sizes; (void)n_in; (void)out_size;
  const int*   x    = (const int*)d_in[0];
  const float* h0   = (const float*)d_in[1];
  const float* c0   = (const float*)d_in[2];
  const float* emb  = (const float*)d_in[3];
  const float* Wih0 = (const float*)d_in[4];
  const float* Whh0 = (const float*)d_in[5];
  const float* Wih1 = (const float*)d_in[6];
  const float* Whh1 = (const float*)d_in[7];
  const float* fcW  = (const float*)d_in[8];
  const float* fcb  = (const float*)d_in[9];
  float* outp = (float*)d_out;

  __hip_bfloat16* wsW = (__hip_bfloat16*)d_ws;

  if (ws_size >= WSB_TOTAL) {
    cvt_pair<<<(WS_PLANE + 255) / 256, 256, 0, stream>>>(Wih0, Whh0, Wih1, Whh1, wsW, 1);
    void* args[] = { (void*)&x, (void*)&h0, (void*)&c0, (void*)&emb, (void*)&wsW,
                     (void*)&fcW, (void*)&fcb, (void*)&outp };
    hipLaunchCooperativeKernel(reinterpret_cast<void*>(lstm_coop),
                               dim3(256), dim3(512), args, 0, stream);
  } else if (ws_size >= WSB_XCHG) {
    cvt_pair<<<(WS_PLANE + 255) / 256, 256, 0, stream>>>(Wih0, Whh0, Wih1, Whh1, wsW, 0);
    lstm_fused<true><<<B_ / RF, 512, 0, stream>>>(
        x, h0, c0, emb, wsW, Wih0, Whh0, Wih1, Whh1, fcW, fcb, outp);
  } else {
    lstm_fused<false><<<B_ / RF, 512, 0, stream>>>(
        x, h0, c0, emb, wsW, Wih0, Whh0, Wih1, Whh1, fcW, fcb, outp);
  }
}